// Round 5
// baseline (82.459 us; speedup 1.0000x reference)
//
#include <hip/hip_runtime.h>

// Log-signature depth 3, d=8, L=256, B=2048 — single fused kernel.
// One block (4 waves) per batch element; wave w scans chunk [64w, 64w+64)
// from zero state (dx row t=255 zeroed = identity step); wave 0 folds:
//   C1=A1+B1; C2=A2+B2+A1⊗B1; C3=A3+B3+A1⊗B2+A2⊗B1.
// Lane l=(i=l>>3, j=l&7): h1=0.5*S1[i], s2=S2[i][j], s3[k]=S3[i][j][k].
//
// KEY (vs R3/R4): the broadcast row operand of the k-loop is neither read
// through the LDS pipe (R3: 24 cyc/step/wave return BW) nor readlane'd
// (R4: SGPR-write hazards). Via Abel summation,
//   sum_u w3_u * dx[t0+u][k] = sum_u (w3_{u-1}-w3_u)*x[t0+u][k]
//                              + w3_63 * x[t0+64][k]   (w3_{-1}=0),
// so the row operand becomes rows of x, which are wave-uniform -> loaded
// with s_load_dwordx16 into SGPRs on the scalar pipe, consumed directly as
// the 1-SGPR operand of each v_fma. Chunk 3 clamps the boundary row to
// x[255]; with dx_255 = 0 the telescoping is exact.
// Per step: 14 VALU, 0 LDS for the row; dxi/dxj = 2x ds_read_b128 / 4 steps
// from the transposed padded LDS image (stride 260, conflict-free).

#define LEN 256
#define DCH 8
#define NW 4
#define CHUNK 64
#define TPAD 260
#define OUTSTRIDE (DCH + DCH*DCH + DCH*DCH*DCH)  // 584

typedef int v16i __attribute__((ext_vector_type(16)));
typedef int v8i  __attribute__((ext_vector_type(8)));

__global__ __launch_bounds__(256) void logsig_fused(const float* __restrict__ x,
                                                    float* __restrict__ out) {
    __shared__ __align__(16) float dxT[DCH][TPAD];   // transposed dx
    __shared__ __align__(16) float sig1[NW][8];
    __shared__ __align__(16) float sig2[NW][64];
    __shared__ __align__(16) float sig3[NW][512];
    __shared__ __align__(16) float s1buf[8];
    __shared__ __align__(16) float s2buf[64];

    const int tid  = threadIdx.x;
    const int w    = tid >> 6;
    const int lane = tid & 63;
    const int i    = lane >> 3;
    const int j    = lane & 7;
    const int b    = blockIdx.x;

    // ---- Stage dx transposed into LDS: dxT[c][t] = x[t+1][c]-x[t][c] ----
    const float4* x4 = (const float4*)(x + (size_t)b * (LEN * DCH));
    for (int f = tid; f < 512; f += 256) {
        float4 dv;
        if (f < 510) {
            float4 a = x4[f];
            float4 c = x4[f + 2];
            dv.x = c.x - a.x; dv.y = c.y - a.y; dv.z = c.z - a.z; dv.w = c.w - a.w;
        } else {
            dv.x = 0.f; dv.y = 0.f; dv.z = 0.f; dv.w = 0.f;  // zero row t=255
        }
        int t  = f >> 1;
        int c0 = (f & 1) * 4;
        dxT[c0 + 0][t] = dv.x;   // bank (4c+t)%32: 2-way at most -> free
        dxT[c0 + 1][t] = dv.y;
        dxT[c0 + 2][t] = dv.z;
        dxT[c0 + 3][t] = dv.w;
    }
    __syncthreads();

    // ---- Chunk scan: 64 steps, rows of x via scalar pipe ----
    const int uw = __builtin_amdgcn_readfirstlane(w);   // provably uniform
    const float* xch = x + (size_t)b * (LEN * DCH) + uw * (CHUNK * DCH);

    float h1 = 0.f, s2 = 0.f, w3p = 0.f;
    float s3[8];
#pragma unroll
    for (int k = 0; k < 8; ++k) s3[k] = 0.f;

    const float c6 = 1.f / 6.f;
    const float* vip = &dxT[i][uw * CHUNK];
    const float* vjp = &dxT[j][uw * CHUNK];

#define STEP(DXI, DXJ, RV, O)                                                 \
    do {                                                                      \
        float dxi = (DXI), dxj = (DXJ);                                       \
        float h1n = fmaf(0.5f, dxi, h1);      /* 0.5*(S1+dxi) */              \
        float tt  = fmaf(c6, dxi, h1);        /* 0.5*S1 + dxi/6 */            \
        float w3  = fmaf(tt, dxj, s2);                                        \
        float wd  = w3p - w3;                                                 \
        s3[0] = fmaf(wd, __int_as_float((RV)[(O) + 0]), s3[0]);               \
        s3[1] = fmaf(wd, __int_as_float((RV)[(O) + 1]), s3[1]);               \
        s3[2] = fmaf(wd, __int_as_float((RV)[(O) + 2]), s3[2]);               \
        s3[3] = fmaf(wd, __int_as_float((RV)[(O) + 3]), s3[3]);               \
        s3[4] = fmaf(wd, __int_as_float((RV)[(O) + 4]), s3[4]);               \
        s3[5] = fmaf(wd, __int_as_float((RV)[(O) + 5]), s3[5]);               \
        s3[6] = fmaf(wd, __int_as_float((RV)[(O) + 6]), s3[6]);               \
        s3[7] = fmaf(wd, __int_as_float((RV)[(O) + 7]), s3[7]);               \
        float tt2 = fmaf(c6, dxi, tt);        /* 0.5*S1 + dxi/3 */            \
        s2 = fmaf(tt2, dxj, w3);              /* tt+tt2 = S1+0.5*dxi */       \
        h1 = h1n; w3p = w3;                                                   \
    } while (0)

    for (int g = 0; g < 16; ++g) {           // 4 steps per group
        v16i ra, rb;                         // rows t0+4g..t0+4g+3 of x
        const float* gp = xch + g * 32;      // uniform scalar address
        asm volatile("s_load_dwordx16 %0, %2, 0\n\t"
                     "s_load_dwordx16 %1, %2, 64\n\t"
                     "s_waitcnt lgkmcnt(0)"
                     : "=s"(ra), "=s"(rb) : "s"(gp));
        float4 vi = *(const float4*)(vip + g * 4);   // ds_read_b128
        float4 vj = *(const float4*)(vjp + g * 4);   // ds_read_b128
        STEP(vi.x, vj.x, ra, 0);
        STEP(vi.y, vj.y, ra, 8);
        STEP(vi.z, vj.z, rb, 0);
        STEP(vi.w, vj.w, rb, 8);
    }
#undef STEP

    // Boundary term: s3 += w3_last * x[min(t0+64,255)]  (clamp is exact,
    // since dx_255 = 0 makes the u=63 telescoping cancel against it).
    {
        int rt = uw * CHUNK + CHUNK;
        if (rt > LEN - 1) rt = LEN - 1;
        const float* bp = x + (size_t)b * (LEN * DCH) + rt * DCH;
        v8i rc;
        asm volatile("s_load_dwordx8 %0, %1, 0\n\t"
                     "s_waitcnt lgkmcnt(0)"
                     : "=s"(rc) : "s"(bp));
#pragma unroll
        for (int k = 0; k < 8; ++k)
            s3[k] = fmaf(w3p, __int_as_float(rc[k]), s3[k]);
    }

    float s1 = h1 + h1;   // S1[i]

    // ---- Publish chunk signatures ----
    if (j == 0) sig1[w][i] = s1;
    sig2[w][lane] = s2;
    float* sp = &sig3[w][lane * 8];
    *(float4*)(sp)     = make_float4(s3[0], s3[1], s3[2], s3[3]);
    *(float4*)(sp + 4) = make_float4(s3[4], s3[5], s3[6], s3[7]);
    __syncthreads();

    if (w != 0) return;

    // ---- Fold chunks 1..3 into wave 0's registers (A=accum, B=chunk c) ----
    for (int c = 1; c < NW; ++c) {
        float B1i  = sig1[c][i];
        float B1j  = sig1[c][j];
        float B2ij = sig2[c][lane];
        float4 b1a = *(const float4*)&sig1[c][0];
        float4 b1b = *(const float4*)&sig1[c][4];
        const float* b2row = &sig2[c][j * 8];
        float4 b2a = *(const float4*)(b2row);
        float4 b2b = *(const float4*)(b2row + 4);
        const float* b3row = &sig3[c][lane * 8];
        float4 b3a = *(const float4*)(b3row);
        float4 b3b = *(const float4*)(b3row + 4);
        float B1k[8]  = {b1a.x, b1a.y, b1a.z, b1a.w, b1b.x, b1b.y, b1b.z, b1b.w};
        float B2jk[8] = {b2a.x, b2a.y, b2a.z, b2a.w, b2b.x, b2b.y, b2b.z, b2b.w};
        float B3[8]   = {b3a.x, b3a.y, b3a.z, b3a.w, b3b.x, b3b.y, b3b.z, b3b.w};
#pragma unroll
        for (int k = 0; k < 8; ++k)   // uses OLD s1 (A1), OLD s2 (A2)
            s3[k] = s3[k] + B3[k] + s1 * B2jk[k] + s2 * B1k[k];
        s2 = s2 + B2ij + s1 * B1j;    // uses OLD s1
        s1 = s1 + B1i;
    }

    // ---- Log map epilogue (wave-internal LDS exchange) ----
    if (j == 0) s1buf[i] = s1;
    s2buf[lane] = s2;

    float S1r[8], S2rj[8];
#pragma unroll
    for (int k = 0; k < 8; ++k) S1r[k] = s1buf[k];
#pragma unroll
    for (int k = 0; k < 8; ++k) S2rj[k] = s2buf[j * 8 + k];
    float s1j = s1buf[j];

    float* ob = out + (size_t)b * OUTSTRIDE;
    if (lane < 8) ob[lane] = s1buf[lane];            // l1
    ob[8 + lane] = fmaf(-0.5f * s1, s1j, s2);        // l2

    float c3 = (1.f / 3.f) * s1 * s1j;
    float l3[8];
#pragma unroll
    for (int k = 0; k < 8; ++k)
        l3[k] = s3[k] - 0.5f * (s1 * S2rj[k] + s2 * S1r[k]) + c3 * S1r[k];
    float* p3 = ob + 72 + lane * 8;
    *(float4*)(p3)     = make_float4(l3[0], l3[1], l3[2], l3[3]);
    *(float4*)(p3 + 4) = make_float4(l3[4], l3[5], l3[6], l3[7]);
}

extern "C" void kernel_launch(void* const* d_in, const int* in_sizes, int n_in,
                              void* d_out, int out_size, void* d_ws, size_t ws_size,
                              hipStream_t stream) {
    const float* x = (const float*)d_in[0];
    float* out = (float*)d_out;
    const int B = in_sizes[0] / (LEN * DCH);   // 2048
    hipLaunchKernelGGL(logsig_fused, dim3(B), dim3(256), 0, stream, x, out);
}